// Round 11
// baseline (304.080 us; speedup 1.0000x reference)
//
#include <hip/hip_runtime.h>
#include <cstdint>
#include <cstddef>

#define DM 1024
#define HEADS 16
#define DHEAD 64
#define SEQ 2048
#define BATCH 2

typedef __bf16 bf16x8 __attribute__((ext_vector_type(8)));
typedef float  f32x4  __attribute__((ext_vector_type(4)));
typedef unsigned short u16;
typedef unsigned int u32;
typedef u16 u16x8 __attribute__((ext_vector_type(8)));
typedef u16 u16x4 __attribute__((ext_vector_type(4)));

__device__ __forceinline__ float bf2f(u16 u){
    union { u32 i; float f; } v; v.i = ((u32)u) << 16; return v.f;
}
__device__ __forceinline__ u16 f2bf(float f){
    union { float f; u32 i; } v; v.f = f;
    u32 r = v.i + 0x7FFF + ((v.i >> 16) & 1);   // RNE
    return (u16)(r >> 16);
}
__device__ __forceinline__ u16 f2bf_rhu(float f){  // cheap round-half-up (positive)
    union { float f; u32 i; } v; v.f = f;
    return (u16)((v.i + 0x8000u) >> 16);
}
__device__ __forceinline__ float fexp2(float x){   // raw v_exp_f32 (2^x)
    float r;
    asm volatile("v_exp_f32 %0, %1\n\ts_nop 1" : "=v"(r) : "v"(x));
    return r;
}
__device__ __forceinline__ void gload16(const u16* g, u16* l){
    __builtin_amdgcn_global_load_lds(
        (const __attribute__((address_space(1))) u32*)g,
        (__attribute__((address_space(3))) u32*)l, 16, 0, 0);
}
// dtype probe from 16 uniform samples of the first input row.
__device__ __forceinline__ int probe_flag(const u16* q){
    int cnt = 0;
    #pragma unroll
    for (int i = 0; i < 32; i += 2){
        int e = (q[i] >> 7) & 0xFF;
        if (e >= 90 && e <= 141) cnt++;
    }
    return (cnt >= 12) ? 1 : 0;
}

// ---------------------------------------------------------------------------
// Merged input prep: cvt3 (3 tensors fp32|bf16 -> bf16) + tcvt4 (4 weight
// matrices transpose+convert), one dispatch (round-10 verified).
//   bid < 6144 : cvt   (z = bid>>11 tensor, 2048 blocks each, 2048 elem/blk)
//   bid >= 6144: tcvt  (z = v>>10 matrix, 32x32 tiles)
// ---------------------------------------------------------------------------
__global__ __launch_bounds__(256) void k_prep(const void* __restrict__ s0,
                                              const void* __restrict__ s1,
                                              const void* __restrict__ s2,
                                              u16* __restrict__ dstbase,
                                              int* __restrict__ hdr, int n,
                                              const void* __restrict__ w0,
                                              const void* __restrict__ w1,
                                              const void* __restrict__ w2,
                                              const void* __restrict__ w3,
                                              u16* __restrict__ wdst){
    __shared__ u16 tile[32][33];
    int bid = blockIdx.x;
    int t = threadIdx.x;
    int isbf = probe_flag((const u16*)s0);
    if (bid < 6144){
        if (bid == 0 && t == 0){
            hdr[0] = isbf;
            #pragma unroll
            for (int c = 1; c <= 24; c++) hdr[c] = 0;
        }
        int z = bid >> 11;
        const void* src = (z == 0) ? s0 : ((z == 1) ? s1 : s2);
        u16* dst = dstbase + (size_t)z * n;
        int i = ((bid & 2047) * 256 + t) * 8;
        if (i >= n) return;
        if (isbf){
            *(u16x8*)&dst[i] = *(const u16x8*)((const u16*)src + i);
        } else {
            const float* s = (const float*)src + i;
            u16x8 o;
            #pragma unroll
            for (int j = 0; j < 8; j++) o[j] = f2bf(s[j]);
            *(u16x8*)&dst[i] = o;
        }
    } else {
        int v = bid - 6144;
        int z = v >> 10, rem = v & 1023;
        const void* src = (z == 0) ? w0 : ((z == 1) ? w1 : ((z == 2) ? w2 : w3));
        u16* dst = wdst + (size_t)z * 1024 * 1024;
        int c0 = (rem & 31) * 32, r0 = (rem >> 5) * 32;
        int tx = t & 31, ty = t >> 5;               // 32 x 8
        #pragma unroll
        for (int i = 0; i < 32; i += 8){
            size_t idx = (size_t)(r0 + ty + i) * 1024 + c0 + tx;
            tile[ty + i][tx] = isbf ? ((const u16*)src)[idx] : f2bf(((const float*)src)[idx]);
        }
        __syncthreads();
        #pragma unroll
        for (int i = 0; i < 32; i += 8)
            dst[(size_t)(c0 + ty + i) * 1024 + r0 + tx] = tile[tx][ty + i];
    }
}

// ---------------------------------------------------------------------------
// Two-barrier GEMM body (round-7/9/10 verified structure, 32 KB LDS, BK=64):
// C[m0..+128, n0..+NJ*32] = A[M,K] x Bt[N,K]^T.
// ---------------------------------------------------------------------------
template<int NJ>
__device__ __forceinline__ void gemm_body2(const u16* __restrict__ A,
                                           const u16* __restrict__ Bt,
                                           u16* __restrict__ C,
                                           int N, int K, int m0, int n0,
                                           u16* lsA, u16* lsB){
    int t = threadIdx.x, lane = t & 63, w = t >> 6;
    int l15 = lane & 15, quad = lane >> 4;
    int wm = (w & 1) * 64, wn = (w >> 1) * (NJ * 16);
    f32x4 acc[4][NJ] = {};
    for (int k0 = 0; k0 < K; k0 += 64){
        __syncthreads();
        #pragma unroll
        for (int j = 0; j < 4; j++){            // A: 128 rows x 8 chunks
            int ub = j * 256 + w * 64;          // wave-uniform unit base
            int u  = ub + lane;
            int r  = u >> 3, cg = (u & 7) ^ (r & 7);
            gload16(&A[(size_t)(m0 + r) * K + k0 + cg * 8], &lsA[ub * 8]);
        }
        #pragma unroll
        for (int j = 0; j < NJ; j++){           // B: NJ*32 rows x 8 chunks
            int ub = j * 256 + w * 64;
            int u  = ub + lane;
            int r  = u >> 3, cg = (u & 7) ^ (r & 7);
            gload16(&Bt[(size_t)(n0 + r) * K + k0 + cg * 8], &lsB[ub * 8]);
        }
        __syncthreads();
        bf16x8 af[4][2], bfr[NJ][2];
        #pragma unroll
        for (int i = 0; i < 4; i++){
            int row = wm + i * 16 + l15;
            #pragma unroll
            for (int kk = 0; kk < 2; kk++)
                af[i][kk] = *(const bf16x8*)&lsA[row * 64 + (((kk * 4 + quad) ^ (row & 7)) * 8)];
        }
        #pragma unroll
        for (int jj = 0; jj < NJ; jj++){
            int row = wn + jj * 16 + l15;
            #pragma unroll
            for (int kk = 0; kk < 2; kk++)
                bfr[jj][kk] = *(const bf16x8*)&lsB[row * 64 + (((kk * 4 + quad) ^ (row & 7)) * 8)];
        }
        #pragma unroll
        for (int i = 0; i < 4; i++)
            #pragma unroll
            for (int jj = 0; jj < NJ; jj++)
                #pragma unroll
                for (int kk = 0; kk < 2; kk++)
                    acc[i][jj] = __builtin_amdgcn_mfma_f32_16x16x32_bf16(af[i][kk], bfr[jj][kk],
                                                                         acc[i][jj], 0, 0, 0);
    }
    #pragma unroll
    for (int i = 0; i < 4; i++)
        #pragma unroll
        for (int jj = 0; jj < NJ; jj++)
            #pragma unroll
            for (int r = 0; r < 4; r++){
                int m = m0 + wm + i * 16 + quad * 4 + r;
                int n = n0 + wn + jj * 16 + l15;
                C[(size_t)m * N + n] = f2bf(acc[i][jj][r]);
            }
}

// ---------------------------------------------------------------------------
// Merged projection dispatch (768 blocks, all 128x128 tiles).
// launch_bounds(256,3): force regs <= ~3-waves/SIMD budget so the 768-block
// grid can run as ONE wave at 3 blocks/CU (768 = 3 x 256 CUs) instead of a
// ragged 512+256 schedule if the allocator drifted past the 2-block budget.
//   bid <  512: QK proj   Qp/Kp[4096,1024] = in_z x WtQ/WtK^T
//   bid >= 512: V^T proj  Vt_b[1024,2048] = WtV x Vi_b^T (written transposed)
// ---------------------------------------------------------------------------
__global__ __launch_bounds__(256, 3) void k_proj(const u16* __restrict__ QKin,
                                                 const u16* __restrict__ Wt,
                                                 u16* __restrict__ QKout,
                                                 const u16* __restrict__ WtV,
                                                 const u16* __restrict__ Vi,
                                                 u16* __restrict__ Vt){
    __shared__ u16 lsA[128 * 64];   // 16 KB
    __shared__ u16 lsB[128 * 64];   // 16 KB
    const size_t MB1 = 1024u * 1024u;
    int bid = blockIdx.x;
    if (bid < 512){
        int z = bid >> 8, r = bid & 255;
        gemm_body2<4>(QKin + (size_t)z * 4 * MB1, Wt + (size_t)z * MB1,
                      QKout + (size_t)z * 4 * MB1, 1024, 1024,
                      (r >> 3) * 128, (r & 7) * 128, lsA, lsB);
    } else {
        int v = bid - 512;
        int z = v >> 7, r = v & 127;
        gemm_body2<4>(WtV, Vi + (size_t)z * 2 * MB1, Vt + (size_t)z * 2 * MB1,
                      2048, 1024, (r >> 4) * 128, (r & 15) * 128, lsA, lsB);
    }
}

// ---------------------------------------------------------------------------
// W_O projection: 128x64 tile, z-batched wrapper over the shared body.
// ---------------------------------------------------------------------------
template<int NJ>
__global__ __launch_bounds__(256, 3) void k_gemmT(const u16* __restrict__ A0,
                                                  const u16* __restrict__ Bt0,
                                                  u16* __restrict__ C0,
                                                  size_t strA, size_t strB, size_t strC,
                                                  int M, int N, int K){
    __shared__ u16 lsA[128 * 64];
    __shared__ u16 lsB[NJ * 32 * 64];
    int z = blockIdx.z;
    gemm_body2<NJ>(A0 + strA * z, Bt0 + strB * z, C0 + strC * z, N, K,
                   blockIdx.y * 128, blockIdx.x * (NJ * 32), lsA, lsB);
    (void)M;
}

// ---------------------------------------------------------------------------
// Fused attention (round-5 verified, UNCHANGED), softmax over HEADS.
// ---------------------------------------------------------------------------
__global__ __launch_bounds__(1024, 4) void k_attn5(const u16* __restrict__ Qp,
                                                   const u16* __restrict__ Kp,
                                                   const u16* __restrict__ Vt,
                                                   u16* __restrict__ c0,
                                                   u16* __restrict__ c1,
                                                   u16* __restrict__ c2,
                                                   u16* __restrict__ c3,
                                                   int* __restrict__ cnt,
                                                   int ncomboM1, int iters){
    __shared__ u16 ebuf[2][16][64][36];   // 144 KB
    __shared__ int s_combo, s_slot;
    int t = threadIdx.x;
    if (t == 0){
        int xcc;
        asm volatile("s_getreg_b32 %0, hwreg(HW_REG_XCC_ID)" : "=s"(xcc));
        int start = xcc & ncomboM1;
        int combo = -1, slot = -1;
        for (int a = 0; a <= ncomboM1 && combo < 0; a++){
            int c = (start + a) & ncomboM1;
            int s = atomicAdd(&cnt[c], 1);
            if (s < 32){ combo = c; slot = s; }
        }
        s_combo = combo; s_slot = slot;
    }
    __syncthreads();
    int combo = s_combo;
    if (combo < 0) return;                 // unreachable; safety for replays
    int b = combo & 1, chunk = combo >> 1;
    int q0 = s_slot * 64;
    int h = t >> 6, lane = t & 63, l15 = lane & 15, quad = lane >> 4;
    u16* outp = (chunk == 0) ? c0 : ((chunk == 1) ? c1 : ((chunk == 2) ? c2 : c3));
    const float cexp = 0.125f * 1.44269504f;
    int kbeg = chunk * (iters << 5);

    bf16x8 qf[4][2];
    #pragma unroll
    for (int sub = 0; sub < 4; sub++)
        #pragma unroll
        for (int ch = 0; ch < 2; ch++)
            qf[sub][ch] = *(const bf16x8*)&Qp[((size_t)(b * SEQ + q0 + sub * 16 + l15)) * DM
                                             + h * DHEAD + ch * 32 + quad * 8];

    f32x4 oacc[4][4] = {};
    int sq = t >> 4, sku = (t & 15) * 2;   // softmax owns (q=sq, k=sku..sku+1)

    auto score_phase = [&](int it){
        int k0 = kbeg + (it << 5), bf = it & 1;
        #pragma unroll
        for (int kt = 0; kt < 2; kt++){
            const u16* kb = Kp + ((size_t)(b * SEQ + k0 + kt * 16 + l15)) * DM + h * DHEAD + quad * 8;
            bf16x8 kf0 = *(const bf16x8*)(kb);
            bf16x8 kf1 = *(const bf16x8*)(kb + 32);
            #pragma unroll
            for (int sub = 0; sub < 4; sub++){
                f32x4 sc = {};
                sc = __builtin_amdgcn_mfma_f32_16x16x32_bf16(qf[sub][0], kf0, sc, 0, 0, 0);
                sc = __builtin_amdgcn_mfma_f32_16x16x32_bf16(qf[sub][1], kf1, sc, 0, 0, 0);
                #pragma unroll
                for (int r = 0; r < 4; r++)
                    ebuf[bf][h][sub * 16 + quad * 4 + r][kt * 16 + l15] =
                        f2bf_rhu(fexp2(sc[r] * cexp));
            }
        }
    };

    score_phase(0);
    for (int it = 0; it < iters; it++){
        int bf = it & 1;
        __syncthreads();                       // B1: e(it) complete
        {   // softmax across 16 heads, in place (u32 = 2 packed bf16)
            u32 ev[16];
            float s0 = 0.f, s1 = 0.f;
            #pragma unroll
            for (int hh = 0; hh < 16; hh++){
                u32 u = *(const u32*)&ebuf[bf][hh][sq][sku];
                ev[hh] = u;
                union { u32 i; float f; } lo, hi;
                lo.i = u << 16; hi.i = u & 0xFFFF0000u;
                s0 += lo.f; s1 += hi.f;
            }
            float r0 = __builtin_amdgcn_rcpf(s0);
            float r1 = __builtin_amdgcn_rcpf(s1);
            #pragma unroll
            for (int hh = 0; hh < 16; hh++){
                union { u32 i; float f; } lo, hi, p0, p1;
                lo.i = ev[hh] << 16; hi.i = ev[hh] & 0xFFFF0000u;
                p0.f = lo.f * r0; p1.f = hi.f * r1;
                *(u32*)&ebuf[bf][hh][sq][sku] =
                    __builtin_amdgcn_perm(p1.i + 0x8000u, p0.i + 0x8000u, 0x07060302u);
            }
        }
        __syncthreads();                       // B2: P(it) ready
        int k0 = kbeg + (it << 5);
        bf16x8 pa[4];
        #pragma unroll
        for (int sub = 0; sub < 4; sub++){
            const u16* pp = &ebuf[bf][h][sub * 16 + l15][quad * 8];
            union { bf16x8 v; u16x4 q[2]; } pu;
            pu.q[0] = *(const u16x4*)pp;
            pu.q[1] = *(const u16x4*)(pp + 4);
            pa[sub] = pu.v;
        }
        #pragma unroll
        for (int vt = 0; vt < 4; vt++){
            bf16x8 vf = *(const bf16x8*)&Vt[((size_t)b * DM + h * DHEAD + vt * 16 + l15) * SEQ
                                            + k0 + quad * 8];
            #pragma unroll
            for (int sub = 0; sub < 4; sub++)
                oacc[sub][vt] = __builtin_amdgcn_mfma_f32_16x16x32_bf16(pa[sub], vf, oacc[sub][vt], 0, 0, 0);
        }
        if (it + 1 < iters) score_phase(it + 1);
    }
    #pragma unroll
    for (int sub = 0; sub < 4; sub++)
        #pragma unroll
        for (int vt = 0; vt < 4; vt++)
            #pragma unroll
            for (int r = 0; r < 4; r++){
                int q = q0 + sub * 16 + quad * 4 + r;
                int n = h * DHEAD + vt * 16 + l15;
                outp[((size_t)b * SEQ + q) * DM + n] = f2bf(oacc[sub][vt][r]);
            }
}

// ---------------------------------------------------------------------------
// dst = c0+c1(+c2+c3) (bf16). dst may alias c0 (same-index load-then-store).
// ---------------------------------------------------------------------------
__global__ __launch_bounds__(256) void k_reduce(const u16* __restrict__ a,
                                                const u16* __restrict__ b,
                                                const u16* __restrict__ c,
                                                const u16* __restrict__ d,
                                                u16* __restrict__ dst, int n, int nch){
    int i = (blockIdx.x * 256 + threadIdx.x) * 8;
    if (i >= n) return;
    u16x8 x = *(const u16x8*)&a[i];
    u16x8 y = *(const u16x8*)&b[i];
    u16x8 o;
    if (nch == 4){
        u16x8 zc = *(const u16x8*)&c[i];
        u16x8 zd = *(const u16x8*)&d[i];
        #pragma unroll
        for (int j = 0; j < 8; j++)
            o[j] = f2bf((bf2f(x[j]) + bf2f(y[j])) + (bf2f(zc[j]) + bf2f(zd[j])));
    } else {
        #pragma unroll
        for (int j = 0; j < 8; j++) o[j] = f2bf(bf2f(x[j]) + bf2f(y[j]));
    }
    *(u16x8*)&dst[i] = o;
}

// ---------------------------------------------------------------------------
// Residual + LayerNorm over last dim (1024). Vectorized (round-9 verified):
// 2 rows/block, 128 threads x 8 elems per row.
// ---------------------------------------------------------------------------
__global__ __launch_bounds__(256) void k_ln(const u16* __restrict__ O,
                                            const void* __restrict__ Qin,
                                            const void* __restrict__ gamma,
                                            const void* __restrict__ beta,
                                            void* __restrict__ out,
                                            const int* __restrict__ flag){
    __shared__ float red[2][2][2];   // [row-in-block][wave-in-row][s1/s2]
    bool isbf = (*flag != 0);
    int t = threadIdx.x;
    int rr = t >> 7, tt = t & 127;
    size_t row = (size_t)blockIdx.x * 2 + rr;
    int idx = tt * 8;
    u16x8 ov = *(const u16x8*)(O + row * DM + idx);
    float x[8];
    if (isbf){
        u16x8 qv = *(const u16x8*)((const u16*)Qin + row * DM + idx);
        #pragma unroll
        for (int j = 0; j < 8; j++) x[j] = bf2f(ov[j]) + bf2f(qv[j]);
    } else {
        const float* qp = (const float*)Qin + row * DM + idx;
        f32x4 q0 = *(const f32x4*)qp, q1 = *(const f32x4*)(qp + 4);
        #pragma unroll
        for (int j = 0; j < 4; j++){
            x[j]     = bf2f(ov[j])     + q0[j];
            x[j + 4] = bf2f(ov[j + 4]) + q1[j];
        }
    }
    float s1 = 0.f, s2 = 0.f;
    #pragma unroll
    for (int j = 0; j < 8; j++){ s1 += x[j]; s2 += x[j] * x[j]; }
    #pragma unroll
    for (int off = 32; off; off >>= 1){
        s1 += __shfl_down(s1, off);
        s2 += __shfl_down(s2, off);
    }
    int wir = (t >> 6) & 1, lane = t & 63;
    if (lane == 0){ red[rr][wir][0] = s1; red[rr][wir][1] = s2; }
    __syncthreads();
    float S1 = red[rr][0][0] + red[rr][1][0];
    float S2 = red[rr][0][1] + red[rr][1][1];
    float mu   = S1 * (1.0f / DM);
    float var  = S2 * (1.0f / DM) - mu * mu;
    float rstd = rsqrtf(var + 1e-5f);
    if (isbf){
        u16x8 gv = *(const u16x8*)((const u16*)gamma + idx);
        u16x8 bv = *(const u16x8*)((const u16*)beta  + idx);
        u16x8 o;
        #pragma unroll
        for (int j = 0; j < 8; j++)
            o[j] = f2bf((x[j] - mu) * rstd * bf2f(gv[j]) + bf2f(bv[j]));
        *(u16x8*)((u16*)out + row * DM + idx) = o;
    } else {
        const float* gp = (const float*)gamma + idx;
        const float* bp = (const float*)beta  + idx;
        f32x4 g0 = *(const f32x4*)gp, g1 = *(const f32x4*)(gp + 4);
        f32x4 b0 = *(const f32x4*)bp, b1 = *(const f32x4*)(bp + 4);
        f32x4 o0, o1;
        #pragma unroll
        for (int j = 0; j < 4; j++){
            o0[j] = (x[j]     - mu) * rstd * g0[j] + b0[j];
            o1[j] = (x[j + 4] - mu) * rstd * g1[j] + b1[j];
        }
        float* op = (float*)out + row * DM + idx;
        *(f32x4*)op = o0; *(f32x4*)(op + 4) = o1;
    }
}

// ---------------------------------------------------------------------------
extern "C" void kernel_launch(void* const* d_in, const int* in_sizes, int n_in,
                              void* d_out, int out_size, void* d_ws, size_t ws_size,
                              hipStream_t stream){
    (void)in_sizes; (void)n_in; (void)out_size;
    const void* inQ = d_in[0];
    const void* inK = d_in[1];
    const void* inV = d_in[2];
    const void* wQ  = d_in[3];
    const void* wK  = d_in[4];
    const void* wV  = d_in[5];
    const void* wO  = d_in[6];
    const void* gma = d_in[7];
    const void* bta = d_in[8];

    int* hdr  = (int*)d_ws;                    // [0]=flag, [1..24]=claim counters
    int* flag = hdr;
    int* cnt  = hdr + 1;
    u16* base = (u16*)d_ws + 64;               // 128 B header

    const size_t MB1 = 1024u * 1024u;          // elements
    const size_t M4  = 4u * MB1;
    u16* Qi  = base + 0;                       // slot0: bf16 Q input -> ctxp0
    u16* Ki  = base + 1 * M4;                  // slot1: bf16 K input -> ctxp1
    u16* Vi  = base + 2 * M4;                  // slot2: bf16 V input -> ctxp2
    u16* WtQ = base + 3 * M4;                  // slot3: 4 x W^T [1024,1024]
    u16* WtV = WtQ + 2 * MB1;
    u16* WtO = WtQ + 3 * MB1;
    u16* Qp  = base + 4 * M4;                  // slot4: Q proj -> Ob
    u16* Kp  = base + 5 * M4;                  // slot5: K proj
    u16* Vp  = base + 6 * M4;                  // slot6: V^T [2][1024][2048]
    u16* ext = base + 7 * M4;                  // slot7: ctxp3 (if ws allows)
    u16* Vt    = Vp;
    u16* ctxp0 = Qi;
    u16* ctxp1 = Ki;
    u16* ctxp2 = Vi;

    size_t need4 = 128 + 8 * M4 * sizeof(u16);
    int nch = (ws_size >= need4) ? 4 : 2;
    u16* ctxp3 = (nch == 4) ? ext : ctxp2;     // dummy when nch==2 (never selected)
    int ncomboM1 = 2 * nch - 1;
    int iters   = (nch == 4) ? 16 : 32;        // keys per chunk / 32
    int ablocks = 32 * 2 * nch;

    const int nIn = BATCH * SEQ * DM;          // 4M
    // merged input conversion + weight transpose (+ flag publish, cnt zero)
    k_prep<<<10240, 256, 0, stream>>>(inQ, inK, inV, base, hdr, nIn,
                                      wQ, wK, wV, wO, WtQ);

    // Q/K projections + transposed V projection, one 768-block dispatch (3/CU)
    k_proj<<<768, 256, 0, stream>>>(Qi, WtQ, Qp, WtV, Vi, Vt);

    k_attn5<<<ablocks, 1024, 0, stream>>>(Qp, Kp, Vt, ctxp0, ctxp1, ctxp2, ctxp3,
                                          cnt, ncomboM1, iters);

    k_reduce<<<nIn / 2048, 256, 0, stream>>>(ctxp0, ctxp1, ctxp2, ctxp3, ctxp0, nIn, nch);

    // W_O projection: 128x64 tile -> 512 blocks
    k_gemmT<2><<<dim3(16, 32, 1), 256, 0, stream>>>(ctxp0, WtO, Qp, 0, 0, 0, 4096, 1024, 1024);

    k_ln<<<2048, 256, 0, stream>>>(Qp, inQ, gma, bta, d_out, flag);
}

// Round 12
// 298.599 us; speedup vs baseline: 1.0184x; 1.0184x over previous
//
#include <hip/hip_runtime.h>
#include <cstdint>
#include <cstddef>

#define DM 1024
#define HEADS 16
#define DHEAD 64
#define SEQ 2048
#define BATCH 2

typedef __bf16 bf16x8 __attribute__((ext_vector_type(8)));
typedef float  f32x4  __attribute__((ext_vector_type(4)));
typedef unsigned short u16;
typedef unsigned int u32;
typedef u16 u16x8 __attribute__((ext_vector_type(8)));
typedef u16 u16x4 __attribute__((ext_vector_type(4)));

__device__ __forceinline__ float bf2f(u16 u){
    union { u32 i; float f; } v; v.i = ((u32)u) << 16; return v.f;
}
__device__ __forceinline__ u16 f2bf(float f){
    union { float f; u32 i; } v; v.f = f;
    u32 r = v.i + 0x7FFF + ((v.i >> 16) & 1);   // RNE
    return (u16)(r >> 16);
}
__device__ __forceinline__ u16 f2bf_rhu(float f){  // cheap round-half-up (positive)
    union { float f; u32 i; } v; v.f = f;
    return (u16)((v.i + 0x8000u) >> 16);
}
__device__ __forceinline__ float fexp2(float x){   // raw v_exp_f32 (2^x)
    float r;
    asm volatile("v_exp_f32 %0, %1\n\ts_nop 1" : "=v"(r) : "v"(x));
    return r;
}
__device__ __forceinline__ void gload16(const u16* g, u16* l){
    __builtin_amdgcn_global_load_lds(
        (const __attribute__((address_space(1))) u32*)g,
        (__attribute__((address_space(3))) u32*)l, 16, 0, 0);
}
// dtype probe from 16 uniform samples of the first input row.
__device__ __forceinline__ int probe_flag(const u16* q){
    int cnt = 0;
    #pragma unroll
    for (int i = 0; i < 32; i += 2){
        int e = (q[i] >> 7) & 0xFF;
        if (e >= 90 && e <= 141) cnt++;
    }
    return (cnt >= 12) ? 1 : 0;
}

// ---------------------------------------------------------------------------
// Merged input prep: cvt3 (3 tensors fp32|bf16 -> bf16) + tcvt4 (4 weight
// matrices transpose+convert), one dispatch (round-10 verified).
//   bid < 6144 : cvt   (z = bid>>11 tensor, 2048 blocks each, 2048 elem/blk)
//   bid >= 6144: tcvt  (z = v>>10 matrix, 32x32 tiles)
// ---------------------------------------------------------------------------
__global__ __launch_bounds__(256) void k_prep(const void* __restrict__ s0,
                                              const void* __restrict__ s1,
                                              const void* __restrict__ s2,
                                              u16* __restrict__ dstbase,
                                              int* __restrict__ hdr, int n,
                                              const void* __restrict__ w0,
                                              const void* __restrict__ w1,
                                              const void* __restrict__ w2,
                                              const void* __restrict__ w3,
                                              u16* __restrict__ wdst){
    __shared__ u16 tile[32][33];
    int bid = blockIdx.x;
    int t = threadIdx.x;
    int isbf = probe_flag((const u16*)s0);
    if (bid < 6144){
        if (bid == 0 && t == 0){
            hdr[0] = isbf;
            #pragma unroll
            for (int c = 1; c <= 24; c++) hdr[c] = 0;
        }
        int z = bid >> 11;
        const void* src = (z == 0) ? s0 : ((z == 1) ? s1 : s2);
        u16* dst = dstbase + (size_t)z * n;
        int i = ((bid & 2047) * 256 + t) * 8;
        if (i >= n) return;
        if (isbf){
            *(u16x8*)&dst[i] = *(const u16x8*)((const u16*)src + i);
        } else {
            const float* s = (const float*)src + i;
            u16x8 o;
            #pragma unroll
            for (int j = 0; j < 8; j++) o[j] = f2bf(s[j]);
            *(u16x8*)&dst[i] = o;
        }
    } else {
        int v = bid - 6144;
        int z = v >> 10, rem = v & 1023;
        const void* src = (z == 0) ? w0 : ((z == 1) ? w1 : ((z == 2) ? w2 : w3));
        u16* dst = wdst + (size_t)z * 1024 * 1024;
        int c0 = (rem & 31) * 32, r0 = (rem >> 5) * 32;
        int tx = t & 31, ty = t >> 5;               // 32 x 8
        #pragma unroll
        for (int i = 0; i < 32; i += 8){
            size_t idx = (size_t)(r0 + ty + i) * 1024 + c0 + tx;
            tile[ty + i][tx] = isbf ? ((const u16*)src)[idx] : f2bf(((const float*)src)[idx]);
        }
        __syncthreads();
        #pragma unroll
        for (int i = 0; i < 32; i += 8)
            dst[(size_t)(c0 + ty + i) * 1024 + r0 + tx] = tile[tx][ty + i];
    }
}

// ---------------------------------------------------------------------------
// Two-barrier GEMM body (round-7/9/10 verified structure, 32 KB LDS, BK=64):
// C[m0..+128, n0..+NJ*32] = A[M,K] x Bt[N,K]^T.
// ---------------------------------------------------------------------------
template<int NJ>
__device__ __forceinline__ void gemm_body2(const u16* __restrict__ A,
                                           const u16* __restrict__ Bt,
                                           u16* __restrict__ C,
                                           int N, int K, int m0, int n0,
                                           u16* lsA, u16* lsB){
    int t = threadIdx.x, lane = t & 63, w = t >> 6;
    int l15 = lane & 15, quad = lane >> 4;
    int wm = (w & 1) * 64, wn = (w >> 1) * (NJ * 16);
    f32x4 acc[4][NJ] = {};
    for (int k0 = 0; k0 < K; k0 += 64){
        __syncthreads();
        #pragma unroll
        for (int j = 0; j < 4; j++){            // A: 128 rows x 8 chunks
            int ub = j * 256 + w * 64;          // wave-uniform unit base
            int u  = ub + lane;
            int r  = u >> 3, cg = (u & 7) ^ (r & 7);
            gload16(&A[(size_t)(m0 + r) * K + k0 + cg * 8], &lsA[ub * 8]);
        }
        #pragma unroll
        for (int j = 0; j < NJ; j++){           // B: NJ*32 rows x 8 chunks
            int ub = j * 256 + w * 64;
            int u  = ub + lane;
            int r  = u >> 3, cg = (u & 7) ^ (r & 7);
            gload16(&Bt[(size_t)(n0 + r) * K + k0 + cg * 8], &lsB[ub * 8]);
        }
        __syncthreads();
        bf16x8 af[4][2], bfr[NJ][2];
        #pragma unroll
        for (int i = 0; i < 4; i++){
            int row = wm + i * 16 + l15;
            #pragma unroll
            for (int kk = 0; kk < 2; kk++)
                af[i][kk] = *(const bf16x8*)&lsA[row * 64 + (((kk * 4 + quad) ^ (row & 7)) * 8)];
        }
        #pragma unroll
        for (int jj = 0; jj < NJ; jj++){
            int row = wn + jj * 16 + l15;
            #pragma unroll
            for (int kk = 0; kk < 2; kk++)
                bfr[jj][kk] = *(const bf16x8*)&lsB[row * 64 + (((kk * 4 + quad) ^ (row & 7)) * 8)];
        }
        #pragma unroll
        for (int i = 0; i < 4; i++)
            #pragma unroll
            for (int jj = 0; jj < NJ; jj++)
                #pragma unroll
                for (int kk = 0; kk < 2; kk++)
                    acc[i][jj] = __builtin_amdgcn_mfma_f32_16x16x32_bf16(af[i][kk], bfr[jj][kk],
                                                                         acc[i][jj], 0, 0, 0);
    }
    #pragma unroll
    for (int i = 0; i < 4; i++)
        #pragma unroll
        for (int jj = 0; jj < NJ; jj++)
            #pragma unroll
            for (int r = 0; r < 4; r++){
                int m = m0 + wm + i * 16 + quad * 4 + r;
                int n = n0 + wn + jj * 16 + l15;
                C[(size_t)m * N + n] = f2bf(acc[i][jj][r]);
            }
}

// ---------------------------------------------------------------------------
// Merged projection dispatch (768 blocks, all 128x128 tiles).
// QK segment: XCD-chunked swizzle (T1). Default mapping pins n0 == XCD id
// (bid%8), so each XCD streams ALL of A (8MB > 4MB L2, zero reuse). Swizzle
// rs=(r&7)*32+(r>>3) gives each XCD a contiguous 4m x 8n sub-grid: A 1MB
// (8x L2 reuse) + B 2MB (4x reuse) = 3MB/XCD, fully L2-resident. Bijective
// (256 % 8 == 0, m204 criterion); z-segments stay phase-aligned (256%8==0).
// Vt segment: default mapping already lands 2.5MB/XCD -> left unswizzled.
// ---------------------------------------------------------------------------
__global__ __launch_bounds__(256, 3) void k_proj(const u16* __restrict__ QKin,
                                                 const u16* __restrict__ Wt,
                                                 u16* __restrict__ QKout,
                                                 const u16* __restrict__ WtV,
                                                 const u16* __restrict__ Vi,
                                                 u16* __restrict__ Vt){
    __shared__ u16 lsA[128 * 64];   // 16 KB
    __shared__ u16 lsB[128 * 64];   // 16 KB
    const size_t MB1 = 1024u * 1024u;
    int bid = blockIdx.x;
    if (bid < 512){
        int z = bid >> 8, r = bid & 255;
        int rs = (r & 7) * 32 + (r >> 3);      // XCD-chunked remap
        gemm_body2<4>(QKin + (size_t)z * 4 * MB1, Wt + (size_t)z * MB1,
                      QKout + (size_t)z * 4 * MB1, 1024, 1024,
                      (rs >> 3) * 128, (rs & 7) * 128, lsA, lsB);
    } else {
        int v = bid - 512;
        int z = v >> 7, r = v & 127;
        gemm_body2<4>(WtV, Vi + (size_t)z * 2 * MB1, Vt + (size_t)z * 2 * MB1,
                      2048, 1024, (r >> 4) * 128, (r & 15) * 128, lsA, lsB);
    }
}

// ---------------------------------------------------------------------------
// W_O projection: 512 blocks (1-D), 128x64 tile, XCD-chunked swizzle.
// Default dim3(16,32) mapping pins n-tile == XCD (bid%8 == x%8) -> A=ctx 8MB
// streams through every XCD L2. Swizzle bs=(bid&7)*64+(bid>>3): each XCD
// gets 4 m-panels (A 1MB, 16x reuse) x all 16 n (B 2MB, 4x reuse) = 3MB/XCD.
// ---------------------------------------------------------------------------
__global__ __launch_bounds__(256, 3) void k_wo(const u16* __restrict__ ctx,
                                               const u16* __restrict__ WtO,
                                               u16* __restrict__ Ob){
    __shared__ u16 lsA[128 * 64];
    __shared__ u16 lsB[64 * 64];
    int bid = blockIdx.x;
    int bs = (bid & 7) * 64 + (bid >> 3);      // XCD-chunked remap (512 % 8 == 0)
    gemm_body2<2>(ctx, WtO, Ob, 1024, 1024,
                  (bs >> 4) * 128, (bs & 15) * 64, lsA, lsB);
}

// ---------------------------------------------------------------------------
// Fused attention (round-5 verified, UNCHANGED), softmax over HEADS.
// ---------------------------------------------------------------------------
__global__ __launch_bounds__(1024, 4) void k_attn5(const u16* __restrict__ Qp,
                                                   const u16* __restrict__ Kp,
                                                   const u16* __restrict__ Vt,
                                                   u16* __restrict__ c0,
                                                   u16* __restrict__ c1,
                                                   u16* __restrict__ c2,
                                                   u16* __restrict__ c3,
                                                   int* __restrict__ cnt,
                                                   int ncomboM1, int iters){
    __shared__ u16 ebuf[2][16][64][36];   // 144 KB
    __shared__ int s_combo, s_slot;
    int t = threadIdx.x;
    if (t == 0){
        int xcc;
        asm volatile("s_getreg_b32 %0, hwreg(HW_REG_XCC_ID)" : "=s"(xcc));
        int start = xcc & ncomboM1;
        int combo = -1, slot = -1;
        for (int a = 0; a <= ncomboM1 && combo < 0; a++){
            int c = (start + a) & ncomboM1;
            int s = atomicAdd(&cnt[c], 1);
            if (s < 32){ combo = c; slot = s; }
        }
        s_combo = combo; s_slot = slot;
    }
    __syncthreads();
    int combo = s_combo;
    if (combo < 0) return;                 // unreachable; safety for replays
    int b = combo & 1, chunk = combo >> 1;
    int q0 = s_slot * 64;
    int h = t >> 6, lane = t & 63, l15 = lane & 15, quad = lane >> 4;
    u16* outp = (chunk == 0) ? c0 : ((chunk == 1) ? c1 : ((chunk == 2) ? c2 : c3));
    const float cexp = 0.125f * 1.44269504f;
    int kbeg = chunk * (iters << 5);

    bf16x8 qf[4][2];
    #pragma unroll
    for (int sub = 0; sub < 4; sub++)
        #pragma unroll
        for (int ch = 0; ch < 2; ch++)
            qf[sub][ch] = *(const bf16x8*)&Qp[((size_t)(b * SEQ + q0 + sub * 16 + l15)) * DM
                                             + h * DHEAD + ch * 32 + quad * 8];

    f32x4 oacc[4][4] = {};
    int sq = t >> 4, sku = (t & 15) * 2;   // softmax owns (q=sq, k=sku..sku+1)

    auto score_phase = [&](int it){
        int k0 = kbeg + (it << 5), bf = it & 1;
        #pragma unroll
        for (int kt = 0; kt < 2; kt++){
            const u16* kb = Kp + ((size_t)(b * SEQ + k0 + kt * 16 + l15)) * DM + h * DHEAD + quad * 8;
            bf16x8 kf0 = *(const bf16x8*)(kb);
            bf16x8 kf1 = *(const bf16x8*)(kb + 32);
            #pragma unroll
            for (int sub = 0; sub < 4; sub++){
                f32x4 sc = {};
                sc = __builtin_amdgcn_mfma_f32_16x16x32_bf16(qf[sub][0], kf0, sc, 0, 0, 0);
                sc = __builtin_amdgcn_mfma_f32_16x16x32_bf16(qf[sub][1], kf1, sc, 0, 0, 0);
                #pragma unroll
                for (int r = 0; r < 4; r++)
                    ebuf[bf][h][sub * 16 + quad * 4 + r][kt * 16 + l15] =
                        f2bf_rhu(fexp2(sc[r] * cexp));
            }
        }
    };

    score_phase(0);
    for (int it = 0; it < iters; it++){
        int bf = it & 1;
        __syncthreads();                       // B1: e(it) complete
        {   // softmax across 16 heads, in place (u32 = 2 packed bf16)
            u32 ev[16];
            float s0 = 0.f, s1 = 0.f;
            #pragma unroll
            for (int hh = 0; hh < 16; hh++){
                u32 u = *(const u32*)&ebuf[bf][hh][sq][sku];
                ev[hh] = u;
                union { u32 i; float f; } lo, hi;
                lo.i = u << 16; hi.i = u & 0xFFFF0000u;
                s0 += lo.f; s1 += hi.f;
            }
            float r0 = __builtin_amdgcn_rcpf(s0);
            float r1 = __builtin_amdgcn_rcpf(s1);
            #pragma unroll
            for (int hh = 0; hh < 16; hh++){
                union { u32 i; float f; } lo, hi, p0, p1;
                lo.i = ev[hh] << 16; hi.i = ev[hh] & 0xFFFF0000u;
                p0.f = lo.f * r0; p1.f = hi.f * r1;
                *(u32*)&ebuf[bf][hh][sq][sku] =
                    __builtin_amdgcn_perm(p1.i + 0x8000u, p0.i + 0x8000u, 0x07060302u);
            }
        }
        __syncthreads();                       // B2: P(it) ready
        int k0 = kbeg + (it << 5);
        bf16x8 pa[4];
        #pragma unroll
        for (int sub = 0; sub < 4; sub++){
            const u16* pp = &ebuf[bf][h][sub * 16 + l15][quad * 8];
            union { bf16x8 v; u16x4 q[2]; } pu;
            pu.q[0] = *(const u16x4*)pp;
            pu.q[1] = *(const u16x4*)(pp + 4);
            pa[sub] = pu.v;
        }
        #pragma unroll
        for (int vt = 0; vt < 4; vt++){
            bf16x8 vf = *(const bf16x8*)&Vt[((size_t)b * DM + h * DHEAD + vt * 16 + l15) * SEQ
                                            + k0 + quad * 8];
            #pragma unroll
            for (int sub = 0; sub < 4; sub++)
                oacc[sub][vt] = __builtin_amdgcn_mfma_f32_16x16x32_bf16(pa[sub], vf, oacc[sub][vt], 0, 0, 0);
        }
        if (it + 1 < iters) score_phase(it + 1);
    }
    #pragma unroll
    for (int sub = 0; sub < 4; sub++)
        #pragma unroll
        for (int vt = 0; vt < 4; vt++)
            #pragma unroll
            for (int r = 0; r < 4; r++){
                int q = q0 + sub * 16 + quad * 4 + r;
                int n = h * DHEAD + vt * 16 + l15;
                outp[((size_t)b * SEQ + q) * DM + n] = f2bf(oacc[sub][vt][r]);
            }
}

// ---------------------------------------------------------------------------
// dst = c0+c1(+c2+c3) (bf16). dst may alias c0 (same-index load-then-store).
// ---------------------------------------------------------------------------
__global__ __launch_bounds__(256) void k_reduce(const u16* __restrict__ a,
                                                const u16* __restrict__ b,
                                                const u16* __restrict__ c,
                                                const u16* __restrict__ d,
                                                u16* __restrict__ dst, int n, int nch){
    int i = (blockIdx.x * 256 + threadIdx.x) * 8;
    if (i >= n) return;
    u16x8 x = *(const u16x8*)&a[i];
    u16x8 y = *(const u16x8*)&b[i];
    u16x8 o;
    if (nch == 4){
        u16x8 zc = *(const u16x8*)&c[i];
        u16x8 zd = *(const u16x8*)&d[i];
        #pragma unroll
        for (int j = 0; j < 8; j++)
            o[j] = f2bf((bf2f(x[j]) + bf2f(y[j])) + (bf2f(zc[j]) + bf2f(zd[j])));
    } else {
        #pragma unroll
        for (int j = 0; j < 8; j++) o[j] = f2bf(bf2f(x[j]) + bf2f(y[j]));
    }
    *(u16x8*)&dst[i] = o;
}

// ---------------------------------------------------------------------------
// Residual + LayerNorm over last dim (1024). Vectorized (round-9 verified):
// 2 rows/block, 128 threads x 8 elems per row.
// ---------------------------------------------------------------------------
__global__ __launch_bounds__(256) void k_ln(const u16* __restrict__ O,
                                            const void* __restrict__ Qin,
                                            const void* __restrict__ gamma,
                                            const void* __restrict__ beta,
                                            void* __restrict__ out,
                                            const int* __restrict__ flag){
    __shared__ float red[2][2][2];   // [row-in-block][wave-in-row][s1/s2]
    bool isbf = (*flag != 0);
    int t = threadIdx.x;
    int rr = t >> 7, tt = t & 127;
    size_t row = (size_t)blockIdx.x * 2 + rr;
    int idx = tt * 8;
    u16x8 ov = *(const u16x8*)(O + row * DM + idx);
    float x[8];
    if (isbf){
        u16x8 qv = *(const u16x8*)((const u16*)Qin + row * DM + idx);
        #pragma unroll
        for (int j = 0; j < 8; j++) x[j] = bf2f(ov[j]) + bf2f(qv[j]);
    } else {
        const float* qp = (const float*)Qin + row * DM + idx;
        f32x4 q0 = *(const f32x4*)qp, q1 = *(const f32x4*)(qp + 4);
        #pragma unroll
        for (int j = 0; j < 4; j++){
            x[j]     = bf2f(ov[j])     + q0[j];
            x[j + 4] = bf2f(ov[j + 4]) + q1[j];
        }
    }
    float s1 = 0.f, s2 = 0.f;
    #pragma unroll
    for (int j = 0; j < 8; j++){ s1 += x[j]; s2 += x[j] * x[j]; }
    #pragma unroll
    for (int off = 32; off; off >>= 1){
        s1 += __shfl_down(s1, off);
        s2 += __shfl_down(s2, off);
    }
    int wir = (t >> 6) & 1, lane = t & 63;
    if (lane == 0){ red[rr][wir][0] = s1; red[rr][wir][1] = s2; }
    __syncthreads();
    float S1 = red[rr][0][0] + red[rr][1][0];
    float S2 = red[rr][0][1] + red[rr][1][1];
    float mu   = S1 * (1.0f / DM);
    float var  = S2 * (1.0f / DM) - mu * mu;
    float rstd = rsqrtf(var + 1e-5f);
    if (isbf){
        u16x8 gv = *(const u16x8*)((const u16*)gamma + idx);
        u16x8 bv = *(const u16x8*)((const u16*)beta  + idx);
        u16x8 o;
        #pragma unroll
        for (int j = 0; j < 8; j++)
            o[j] = f2bf((x[j] - mu) * rstd * bf2f(gv[j]) + bf2f(bv[j]));
        *(u16x8*)((u16*)out + row * DM + idx) = o;
    } else {
        const float* gp = (const float*)gamma + idx;
        const float* bp = (const float*)beta  + idx;
        f32x4 g0 = *(const f32x4*)gp, g1 = *(const f32x4*)(gp + 4);
        f32x4 b0 = *(const f32x4*)bp, b1 = *(const f32x4*)(bp + 4);
        f32x4 o0, o1;
        #pragma unroll
        for (int j = 0; j < 4; j++){
            o0[j] = (x[j]     - mu) * rstd * g0[j] + b0[j];
            o1[j] = (x[j + 4] - mu) * rstd * g1[j] + b1[j];
        }
        float* op = (float*)out + row * DM + idx;
        *(f32x4*)op = o0; *(f32x4*)(op + 4) = o1;
    }
}

// ---------------------------------------------------------------------------
extern "C" void kernel_launch(void* const* d_in, const int* in_sizes, int n_in,
                              void* d_out, int out_size, void* d_ws, size_t ws_size,
                              hipStream_t stream){
    (void)in_sizes; (void)n_in; (void)out_size;
    const void* inQ = d_in[0];
    const void* inK = d_in[1];
    const void* inV = d_in[2];
    const void* wQ  = d_in[3];
    const void* wK  = d_in[4];
    const void* wV  = d_in[5];
    const void* wO  = d_in[6];
    const void* gma = d_in[7];
    const void* bta = d_in[8];

    int* hdr  = (int*)d_ws;                    // [0]=flag, [1..24]=claim counters
    int* flag = hdr;
    int* cnt  = hdr + 1;
    u16* base = (u16*)d_ws + 64;               // 128 B header

    const size_t MB1 = 1024u * 1024u;          // elements
    const size_t M4  = 4u * MB1;
    u16* Qi  = base + 0;                       // slot0: bf16 Q input -> ctxp0
    u16* Ki  = base + 1 * M4;                  // slot1: bf16 K input -> ctxp1
    u16* Vi  = base + 2 * M4;                  // slot2: bf16 V input -> ctxp2
    u16* WtQ = base + 3 * M4;                  // slot3: 4 x W^T [1024,1024]
    u16* WtV = WtQ + 2 * MB1;
    u16* WtO = WtQ + 3 * MB1;
    u16* Qp  = base + 4 * M4;                  // slot4: Q proj -> Ob
    u16* Kp  = base + 5 * M4;                  // slot5: K proj
    u16* Vp  = base + 6 * M4;                  // slot6: V^T [2][1024][2048]
    u16* ext = base + 7 * M4;                  // slot7: ctxp3 (if ws allows)
    u16* Vt    = Vp;
    u16* ctxp0 = Qi;
    u16* ctxp1 = Ki;
    u16* ctxp2 = Vi;

    size_t need4 = 128 + 8 * M4 * sizeof(u16);
    int nch = (ws_size >= need4) ? 4 : 2;
    u16* ctxp3 = (nch == 4) ? ext : ctxp2;     // dummy when nch==2 (never selected)
    int ncomboM1 = 2 * nch - 1;
    int iters   = (nch == 4) ? 16 : 32;        // keys per chunk / 32
    int ablocks = 32 * 2 * nch;

    const int nIn = BATCH * SEQ * DM;          // 4M
    // merged input conversion + weight transpose (+ flag publish, cnt zero)
    k_prep<<<10240, 256, 0, stream>>>(inQ, inK, inV, base, hdr, nIn,
                                      wQ, wK, wV, wO, WtQ);

    // Q/K projections + transposed V projection, one 768-block dispatch
    k_proj<<<768, 256, 0, stream>>>(Qi, WtQ, Qp, WtV, Vi, Vt);

    k_attn5<<<ablocks, 1024, 0, stream>>>(Qp, Kp, Vt, ctxp0, ctxp1, ctxp2, ctxp3,
                                          cnt, ncomboM1, iters);

    k_reduce<<<nIn / 2048, 256, 0, stream>>>(ctxp0, ctxp1, ctxp2, ctxp3, ctxp0, nIn, nch);

    // W_O projection: 128x64 tile, 512 blocks, XCD-chunked mapping
    k_wo<<<512, 256, 0, stream>>>(ctxp0, WtO, Qp);

    k_ln<<<2048, 256, 0, stream>>>(Qp, inQ, gma, bta, d_out, flag);
}